// Round 7
// baseline (445.815 us; speedup 1.0000x reference)
//
#include <hip/hip_runtime.h>
#include <math.h>

// ---------------------------------------------------------------------------
// GraphSAGE fraud detector. CSR-gather aggregation + bf16 MFMA GEMMs.
// R7: gemm staging via __builtin_amdgcn_global_load_lds width=16 (m97
// lever): no ds_writes, no staging VGPRs, and a DMA-compatible LDS layout
// (16B chunk (row,quad) at slot quad*128+row) whose fragment reads are
// contiguous-1KB per quad -> only the free 2-way lane aliasing (m136).
// R6 had 1.28e7 SQ_LDS_BANK_CONFLICT (~20% of gemm2 time) from the
// padded-row ds_write/ds_read pattern. BK=32 kept (BK=64 spilled, R4/R5).
// MFMA 16x16x32 bf16: A-frag A[m=lane&15][k=quad*8+j]; C/D col=lane&15,
// row=quad*4+reg (m89/m97-verified layouts).
// ---------------------------------------------------------------------------

typedef __attribute__((ext_vector_type(8))) short bf16x8;   // 8 bf16, 4 VGPRs
typedef __attribute__((ext_vector_type(4))) float f32x4;

static inline int ceil_div(int a, int b) { return (a + b - 1) / b; }

__device__ inline float bf2f_lo(unsigned u) { return __builtin_bit_cast(float, u << 16); }
__device__ inline float bf2f_hi(unsigned u) { return __builtin_bit_cast(float, u & 0xffff0000u); }
__device__ inline unsigned f2bf(float f) {   // RNE round to bf16, bits in low 16
    unsigned u = __builtin_bit_cast(unsigned, f);
    u += 0x7fffu + ((u >> 16) & 1u);
    return u >> 16;
}

// async global->LDS, 16 B per lane; LDS dest = wave-uniform base + lane*16
#define GLOAD_LDS16(gp, lp)                                                   \
    __builtin_amdgcn_global_load_lds(                                         \
        (__attribute__((address_space(1))) void*)(gp),                        \
        (__attribute__((address_space(3))) void*)(lp), 16, 0, 0)

// ---------------- CSR build ----------------

__global__ void hist_kernel(const int* __restrict__ dst, int* __restrict__ deg, int E) {
    int e = blockIdx.x * 256 + threadIdx.x;
    if (e < E) atomicAdd(&deg[dst[e]], 1);
}

// per-1024-chunk sums
__global__ __launch_bounds__(256) void chunk_reduce(const int* __restrict__ deg,
                                                    int* __restrict__ partial, int N) {
    int base = blockIdx.x * 1024;
    int s = 0;
    for (int i = threadIdx.x; i < 1024; i += 256) {
        int idx = base + i;
        if (idx < N) s += deg[idx];
    }
    #pragma unroll
    for (int off = 32; off; off >>= 1) s += __shfl_down(s, off);
    __shared__ int ws[4];
    if ((threadIdx.x & 63) == 0) ws[threadIdx.x >> 6] = s;
    __syncthreads();
    if (threadIdx.x == 0) partial[blockIdx.x] = ws[0] + ws[1] + ws[2] + ws[3];
}

// exclusive scan of P<=64 partials (one wave); writes rowstart[N]=total
__global__ void partial_scan(int* __restrict__ partial, int* __restrict__ rowstartN, int P) {
    int lane = threadIdx.x;
    int v = (lane < P) ? partial[lane] : 0;
    int incl = v;
    #pragma unroll
    for (int off = 1; off < 64; off <<= 1) {
        int t = __shfl_up(incl, off);
        if (lane >= off) incl += t;
    }
    if (lane < P) partial[lane] = incl - v;
    if (lane == 63) *rowstartN = incl;
}

// per-chunk exclusive scan + global offset; writes rowstart and cursor
__global__ __launch_bounds__(256) void chunk_scan(const int* __restrict__ deg,
                                                  const int* __restrict__ partial,
                                                  int* __restrict__ rowstart,
                                                  int* __restrict__ cursor, int N) {
    int base = blockIdx.x * 1024 + threadIdx.x * 4;
    int v[4];
    #pragma unroll
    for (int j = 0; j < 4; ++j) {
        int i = base + j;
        v[j] = (i < N) ? deg[i] : 0;
    }
    int mysum = v[0] + v[1] + v[2] + v[3];
    int incl = mysum;
    int lane = threadIdx.x & 63, wave = threadIdx.x >> 6;
    #pragma unroll
    for (int off = 1; off < 64; off <<= 1) {
        int t = __shfl_up(incl, off);
        if (lane >= off) incl += t;
    }
    __shared__ int ws[4];
    if (lane == 63) ws[wave] = incl;
    __syncthreads();
    int run = partial[blockIdx.x] + incl - mysum;
    for (int w = 0; w < wave; ++w) run += ws[w];
    #pragma unroll
    for (int j = 0; j < 4; ++j) {
        int i = base + j;
        if (i < N) { rowstart[i] = run; cursor[i] = run; }
        run += v[j];
    }
}

__global__ void bucket_kernel(const int* __restrict__ src, const int* __restrict__ dst,
                              int* __restrict__ cursor, int* __restrict__ ebuf, int E) {
    int e = blockIdx.x * 256 + threadIdx.x;
    if (e < E) {
        int pos = atomicAdd(&cursor[dst[e]], 1);
        ebuf[pos] = src[e];
    }
}

// ---------------- dtype conversion ----------------

__global__ void cvt_bf16_kernel(const float* __restrict__ in, unsigned short* __restrict__ out, int n4) {
    int i = blockIdx.x * 256 + threadIdx.x;
    if (i < n4) {
        float4 v = ((const float4*)in)[i];
        ushort4 o;
        o.x = (unsigned short)f2bf(v.x);
        o.y = (unsigned short)f2bf(v.y);
        o.z = (unsigned short)f2bf(v.z);
        o.w = (unsigned short)f2bf(v.w);
        ((ushort4*)out)[i] = o;
    }
}

// ---------------- gather means ----------------

// one wave per dst row; bf16 xb [N,128] -> bf16 mean [N,128]; fp32 accum
__global__ void gather_mean_128(const int* __restrict__ rowstart, const int* __restrict__ ebuf,
                                const unsigned* __restrict__ featb, unsigned* __restrict__ outb, int N) {
    int w = (blockIdx.x * blockDim.x + threadIdx.x) >> 6;
    int lane = threadIdx.x & 63;
    if (w >= N) return;
    int e0 = rowstart[w], e1 = rowstart[w + 1];
    float ax = 0.0f, ay = 0.0f;
    for (int i = e0; i < e1; ++i) {
        int s = ebuf[i];
        unsigned v = featb[(size_t)s * 64 + lane];   // 2 bf16
        ax += bf2f_lo(v); ay += bf2f_hi(v);
    }
    float inv = 1.0f / fmaxf((float)(e1 - e0), 1.0f);
    outb[(size_t)w * 64 + lane] = f2bf(ax * inv) | (f2bf(ay * inv) << 16);
}

// one wave per dst row; bf16 feat [N,512] -> bf16 mean [N,512]; fp32 accum
__global__ void gather_mean_512(const int* __restrict__ rowstart, const int* __restrict__ ebuf,
                                const unsigned short* __restrict__ featb,
                                unsigned short* __restrict__ outb, int N) {
    int w = (blockIdx.x * blockDim.x + threadIdx.x) >> 6;
    int lane = threadIdx.x & 63;
    if (w >= N) return;
    int e0 = rowstart[w], e1 = rowstart[w + 1];
    float a[8] = {0, 0, 0, 0, 0, 0, 0, 0};
    const uint4* base = (const uint4*)featb;     // 512 bf16/row = 64 uint4/row
    for (int i = e0; i < e1; ++i) {
        int s = ebuf[i];
        uint4 v = base[(size_t)s * 64 + lane];
        a[0] += bf2f_lo(v.x); a[1] += bf2f_hi(v.x);
        a[2] += bf2f_lo(v.y); a[3] += bf2f_hi(v.y);
        a[4] += bf2f_lo(v.z); a[5] += bf2f_hi(v.z);
        a[6] += bf2f_lo(v.w); a[7] += bf2f_hi(v.w);
    }
    float inv = 1.0f / fmaxf((float)(e1 - e0), 1.0f);
    uint4 o;
    o.x = f2bf(a[0] * inv) | (f2bf(a[1] * inv) << 16);
    o.y = f2bf(a[2] * inv) | (f2bf(a[3] * inv) << 16);
    o.z = f2bf(a[4] * inv) | (f2bf(a[5] * inv) << 16);
    o.w = f2bf(a[6] * inv) | (f2bf(a[7] * inv) << 16);
    ((uint4*)outb)[(size_t)w * 64 + lane] = o;
}

// ---------------- bf16 MFMA GEMM (global_load_lds staging) ----------------
// C = relu([A0b | A1b] @ Wb^T + b)
// mode 0: store C as bf16 to outb [N, C]
// mode 1: logit[row] += sum_col C[row,col] * Wo[col]
// Block 256 thr = 4 waves (2x2); tile 128x128; wave tile 64x64 (4x4 mfma);
// BK=32. Staging: 16 global_load_lds_dwordx4 per block per iter (4/wave).
// LDS layout: 16B chunk (row r, k-quad q) at slot q*128+r -> frag reads are
// contiguous 1KB per quad (free 2-way aliasing only). REQUIRES K0 == K1.
__global__ __launch_bounds__(256) void gemm_mfma(
    const unsigned short* __restrict__ A0,   // [N, K0] bf16
    const unsigned short* __restrict__ A1,   // [N, K1] bf16, K1 == K0
    const unsigned short* __restrict__ W,    // [C, K0+K1] bf16 row-major
    const float* __restrict__ b,             // [C] fp32
    unsigned short* __restrict__ outb,       // [N, C] bf16 (mode 0)
    const float* __restrict__ Wo,            // [C] fp32    (mode 1)
    float* __restrict__ logit,               // [N] fp32    (mode 1)
    int N, int K0, int K1, int C, int mode)
{
    const int K = K0 + K1;
    const int S = K0;               // row stride of both A0 and A1
    __shared__ short As[4096];      // 8 KB
    __shared__ short Bs[4096];      // 8 KB

    const int tid  = threadIdx.x;
    const int lane = tid & 63;
    const int wave = tid >> 6;
    const int wm = wave & 1, wn = wave >> 1;
    const int cl = lane & 15, quad = lane >> 4;
    const int row0 = blockIdx.y * 128;     // rowblk = slow grid dim
    const int col0 = blockIdx.x * 128;     // colblk = fast grid dim

    // staging: this lane DMAs chunks s0 = wave*128+lane and s1 = s0+64.
    // chunk s = q*128 + r  (r = tile row, q = k-quad of 8 bf16)
    const int s0 = wave * 128 + lane;
    const int s1 = s0 + 64;
    const int r0 = s0 & 127, q0 = s0 >> 7;
    const int r1 = s1 & 127, q1 = s1 >> 7;
    // clamp OOB tile rows to N-1: loaded garbage is discarded by epilogue guard
    const int ar0 = (row0 + r0 < N) ? row0 + r0 : N - 1;
    const int ar1 = (row0 + r1 < N) ? row0 + r1 : N - 1;
    const size_t aoff0 = (size_t)ar0 * S + q0 * 8;
    const size_t aoff1 = (size_t)ar1 * S + q1 * 8;
    const size_t boff0 = (size_t)(col0 + r0) * K + q0 * 8;
    const size_t boff1 = (size_t)(col0 + r1) * K + q1 * 8;
    // wave-uniform LDS bases (shorts): load i covers bytes (wave*2+i)*1024..
    short* const lA0 = &As[(wave * 2 + 0) * 512];
    short* const lA1 = &As[(wave * 2 + 1) * 512];
    short* const lB0 = &Bs[(wave * 2 + 0) * 512];
    short* const lB1 = &Bs[(wave * 2 + 1) * 512];

    f32x4 acc[4][4];
    #pragma unroll
    for (int mt = 0; mt < 4; ++mt)
        #pragma unroll
        for (int nt = 0; nt < 4; ++nt)
            acc[mt][nt] = (f32x4){0.f, 0.f, 0.f, 0.f};

    for (int k0 = 0; k0 < K; k0 += 32) {
        // uniform A0/A1 select (K0 multiple of 32)
        const unsigned short* Ab = (k0 < K0) ? (A0 + k0) : (A1 + (k0 - K0));
        const unsigned short* Wb = W + k0;

        __syncthreads();            // previous iteration's frag reads done
        GLOAD_LDS16(Ab + aoff0, lA0);
        GLOAD_LDS16(Ab + aoff1, lA1);
        GLOAD_LDS16(Wb + boff0, lB0);
        GLOAD_LDS16(Wb + boff1, lB1);
        __syncthreads();            // drains vmcnt -> tiles resident

        bf16x8 af[4], bfr[4];
        #pragma unroll
        for (int mt = 0; mt < 4; ++mt)
            af[mt] = *(const bf16x8*)&As[quad * 1024 + (wm * 64 + mt * 16 + cl) * 8];
        #pragma unroll
        for (int nt = 0; nt < 4; ++nt)
            bfr[nt] = *(const bf16x8*)&Bs[quad * 1024 + (wn * 64 + nt * 16 + cl) * 8];

        #pragma unroll
        for (int mt = 0; mt < 4; ++mt)
            #pragma unroll
            for (int nt = 0; nt < 4; ++nt)
                acc[mt][nt] = __builtin_amdgcn_mfma_f32_16x16x32_bf16(
                    af[mt], bfr[nt], acc[mt][nt], 0, 0, 0);
    }

    if (mode == 0) {
        #pragma unroll
        for (int nt = 0; nt < 4; ++nt) {
            const int colb = col0 + wn * 64 + nt * 16 + cl;
            const float bb = b[colb];
            #pragma unroll
            for (int mt = 0; mt < 4; ++mt) {
                #pragma unroll
                for (int r = 0; r < 4; ++r) {
                    int row = row0 + wm * 64 + mt * 16 + quad * 4 + r;
                    if (row < N)
                        outb[(size_t)row * C + colb] =
                            (unsigned short)f2bf(fmaxf(acc[mt][nt][r] + bb, 0.0f));
                }
            }
        }
    } else {
        float bv[4], wv2[4];
        #pragma unroll
        for (int nt = 0; nt < 4; ++nt) {
            const int colb = col0 + wn * 64 + nt * 16 + cl;
            bv[nt] = b[colb];
            wv2[nt] = Wo[colb];
        }
        #pragma unroll
        for (int mt = 0; mt < 4; ++mt) {
            #pragma unroll
            for (int r = 0; r < 4; ++r) {
                float s = 0.0f;
                #pragma unroll
                for (int nt = 0; nt < 4; ++nt)
                    s += fmaxf(acc[mt][nt][r] + bv[nt], 0.0f) * wv2[nt];
                s += __shfl_xor(s, 1);
                s += __shfl_xor(s, 2);
                s += __shfl_xor(s, 4);
                s += __shfl_xor(s, 8);
                int row = row0 + wm * 64 + mt * 16 + quad * 4 + r;
                if (cl == 0 && row < N) atomicAdd(&logit[row], s);
            }
        }
    }
}

__global__ void head_kernel(const float* __restrict__ logit, const float* __restrict__ bo,
                            float* __restrict__ out, int N) {
    int i = blockIdx.x * 256 + threadIdx.x;
    if (i < N) out[i] = 1.0f / (1.0f + expf(-(logit[i] + bo[0])));
}

extern "C" void kernel_launch(void* const* d_in, const int* in_sizes, int n_in,
                              void* d_out, int out_size, void* d_ws, size_t ws_size,
                              hipStream_t stream) {
    const float* x  = (const float*)d_in[0];
    const int*   ei = (const int*)d_in[1];
    const float* W1 = (const float*)d_in[2];
    const float* b1 = (const float*)d_in[3];
    const float* W2 = (const float*)d_in[4];
    const float* b2 = (const float*)d_in[5];
    const float* Wo = (const float*)d_in[6];
    const float* bo = (const float*)d_in[7];
    float* out = (float*)d_out;

    const int N = in_sizes[0] / 128;   // 50000
    const int E = in_sizes[1] / 2;     // 400000
    const int* src = ei;
    const int* dst = ei + E;

    char* ws = (char*)d_ws;
    size_t off = 0;
    auto alloc = [&](size_t bytes) {
        void* p = ws + off;
        off += (bytes + 255) & ~(size_t)255;
        return p;
    };
    int* deg      = (int*)alloc((size_t)N * 4);
    int* rowstart = (int*)alloc((size_t)(N + 1) * 4);
    int* cursor   = (int*)alloc((size_t)N * 4);
    int* partial  = (int*)alloc((size_t)64 * 4);
    int* ebuf     = (int*)alloc((size_t)E * 4);
    float* logit  = (float*)alloc((size_t)N * 4);
    unsigned short* xb  = (unsigned short*)alloc((size_t)N * 128 * 2);
    unsigned short* W1b = (unsigned short*)alloc((size_t)512 * 256 * 2);
    unsigned short* W2b = (unsigned short*)alloc((size_t)512 * 1024 * 2);
    unsigned short* n1b = (unsigned short*)alloc((size_t)N * 128 * 2);
    unsigned short* h1b = (unsigned short*)alloc((size_t)N * 512 * 2);
    unsigned short* n2b = (unsigned short*)alloc((size_t)N * 512 * 2);
    (void)ws_size; (void)n_in; (void)out_size;

    hipMemsetAsync(deg,   0, (size_t)N * 4, stream);
    hipMemsetAsync(logit, 0, (size_t)N * 4, stream);

    // conversions
    cvt_bf16_kernel<<<ceil_div(N * 128 / 4, 256), 256, 0, stream>>>(x, xb, N * 128 / 4);
    cvt_bf16_kernel<<<ceil_div(512 * 256 / 4, 256), 256, 0, stream>>>(W1, W1b, 512 * 256 / 4);
    cvt_bf16_kernel<<<ceil_div(512 * 1024 / 4, 256), 256, 0, stream>>>(W2, W2b, 512 * 1024 / 4);

    // CSR build (hierarchical scan)
    const int P = ceil_div(N, 1024);   // 49
    hist_kernel<<<ceil_div(E, 256), 256, 0, stream>>>(dst, deg, E);
    chunk_reduce<<<P, 256, 0, stream>>>(deg, partial, N);
    partial_scan<<<1, 64, 0, stream>>>(partial, rowstart + N, P);
    chunk_scan<<<P, 256, 0, stream>>>(deg, partial, rowstart, cursor, N);
    bucket_kernel<<<ceil_div(E, 256), 256, 0, stream>>>(src, dst, cursor, ebuf, E);

    dim3 gg(512 / 128, ceil_div(N, 128));   // (colblk fast, rowblk slow)

    // layer 1
    gather_mean_128<<<ceil_div(N * 64, 256), 256, 0, stream>>>(rowstart, ebuf,
                                                               (const unsigned*)xb, (unsigned*)n1b, N);
    gemm_mfma<<<gg, 256, 0, stream>>>(xb, n1b, W1b, b1, h1b, nullptr, nullptr,
                                      N, 128, 128, 512, 0);

    // layer 2 + fused head
    gather_mean_512<<<ceil_div(N * 64, 256), 256, 0, stream>>>(rowstart, ebuf, h1b, n2b, N);
    gemm_mfma<<<gg, 256, 0, stream>>>(h1b, n2b, W2b, b2, nullptr, Wo, logit,
                                      N, 512, 512, 512, 1);

    head_kernel<<<ceil_div(N, 256), 256, 0, stream>>>(logit, bo, out, N);
}

// Round 8
// 419.634 us; speedup vs baseline: 1.0624x; 1.0624x over previous
//
#include <hip/hip_runtime.h>
#include <math.h>

// ---------------------------------------------------------------------------
// GraphSAGE fraud detector. CSR-gather aggregation + bf16 MFMA GEMMs.
// R8: double-buffered global_load_lds GEMM, ONE barrier per K-iter:
//   prefetch tile0; iter i: barrier (drains tile i DMA + fences tile i-1
//   frag reads), issue tile i+1 DMA into other buffer, compute tile i.
// R7 exposed the full DMA latency between its two barriers (141 us,
// MfmaUtil 15%); R6's ds_write path had 1.28e7 LDS conflicts (105 us).
// This keeps R7's conflict-free chunk layout and overlaps the DMA.
// Gathers: manual 2-edge unroll for MLP.
// MFMA 16x16x32 bf16: A-frag A[m=lane&15][k=quad*8+j]; C/D col=lane&15,
// row=quad*4+reg (m89/m97-verified layouts).
// ---------------------------------------------------------------------------

typedef __attribute__((ext_vector_type(8))) short bf16x8;   // 8 bf16, 4 VGPRs
typedef __attribute__((ext_vector_type(4))) float f32x4;

static inline int ceil_div(int a, int b) { return (a + b - 1) / b; }

__device__ inline float bf2f_lo(unsigned u) { return __builtin_bit_cast(float, u << 16); }
__device__ inline float bf2f_hi(unsigned u) { return __builtin_bit_cast(float, u & 0xffff0000u); }
__device__ inline unsigned f2bf(float f) {   // RNE round to bf16, bits in low 16
    unsigned u = __builtin_bit_cast(unsigned, f);
    u += 0x7fffu + ((u >> 16) & 1u);
    return u >> 16;
}

// async global->LDS, 16 B per lane; LDS dest = wave-uniform base + lane*16
#define GLOAD_LDS16(gp, lp)                                                   \
    __builtin_amdgcn_global_load_lds(                                         \
        (__attribute__((address_space(1))) void*)(gp),                        \
        (__attribute__((address_space(3))) void*)(lp), 16, 0, 0)

// ---------------- CSR build ----------------

__global__ void hist_kernel(const int* __restrict__ dst, int* __restrict__ deg, int E) {
    int e = blockIdx.x * 256 + threadIdx.x;
    if (e < E) atomicAdd(&deg[dst[e]], 1);
}

// per-1024-chunk sums
__global__ __launch_bounds__(256) void chunk_reduce(const int* __restrict__ deg,
                                                    int* __restrict__ partial, int N) {
    int base = blockIdx.x * 1024;
    int s = 0;
    for (int i = threadIdx.x; i < 1024; i += 256) {
        int idx = base + i;
        if (idx < N) s += deg[idx];
    }
    #pragma unroll
    for (int off = 32; off; off >>= 1) s += __shfl_down(s, off);
    __shared__ int ws[4];
    if ((threadIdx.x & 63) == 0) ws[threadIdx.x >> 6] = s;
    __syncthreads();
    if (threadIdx.x == 0) partial[blockIdx.x] = ws[0] + ws[1] + ws[2] + ws[3];
}

// exclusive scan of P<=64 partials (one wave); writes rowstart[N]=total
__global__ void partial_scan(int* __restrict__ partial, int* __restrict__ rowstartN, int P) {
    int lane = threadIdx.x;
    int v = (lane < P) ? partial[lane] : 0;
    int incl = v;
    #pragma unroll
    for (int off = 1; off < 64; off <<= 1) {
        int t = __shfl_up(incl, off);
        if (lane >= off) incl += t;
    }
    if (lane < P) partial[lane] = incl - v;
    if (lane == 63) *rowstartN = incl;
}

// per-chunk exclusive scan + global offset; writes rowstart and cursor
__global__ __launch_bounds__(256) void chunk_scan(const int* __restrict__ deg,
                                                  const int* __restrict__ partial,
                                                  int* __restrict__ rowstart,
                                                  int* __restrict__ cursor, int N) {
    int base = blockIdx.x * 1024 + threadIdx.x * 4;
    int v[4];
    #pragma unroll
    for (int j = 0; j < 4; ++j) {
        int i = base + j;
        v[j] = (i < N) ? deg[i] : 0;
    }
    int mysum = v[0] + v[1] + v[2] + v[3];
    int incl = mysum;
    int lane = threadIdx.x & 63, wave = threadIdx.x >> 6;
    #pragma unroll
    for (int off = 1; off < 64; off <<= 1) {
        int t = __shfl_up(incl, off);
        if (lane >= off) incl += t;
    }
    __shared__ int ws[4];
    if (lane == 63) ws[wave] = incl;
    __syncthreads();
    int run = partial[blockIdx.x] + incl - mysum;
    for (int w = 0; w < wave; ++w) run += ws[w];
    #pragma unroll
    for (int j = 0; j < 4; ++j) {
        int i = base + j;
        if (i < N) { rowstart[i] = run; cursor[i] = run; }
        run += v[j];
    }
}

__global__ void bucket_kernel(const int* __restrict__ src, const int* __restrict__ dst,
                              int* __restrict__ cursor, int* __restrict__ ebuf, int E) {
    int e = blockIdx.x * 256 + threadIdx.x;
    if (e < E) {
        int pos = atomicAdd(&cursor[dst[e]], 1);
        ebuf[pos] = src[e];
    }
}

// ---------------- dtype conversion ----------------

__global__ void cvt_bf16_kernel(const float* __restrict__ in, unsigned short* __restrict__ out, int n4) {
    int i = blockIdx.x * 256 + threadIdx.x;
    if (i < n4) {
        float4 v = ((const float4*)in)[i];
        ushort4 o;
        o.x = (unsigned short)f2bf(v.x);
        o.y = (unsigned short)f2bf(v.y);
        o.z = (unsigned short)f2bf(v.z);
        o.w = (unsigned short)f2bf(v.w);
        ((ushort4*)out)[i] = o;
    }
}

// ---------------- gather means ----------------

// one wave per dst row; bf16 xb [N,128] -> bf16 mean [N,128]; fp32 accum
__global__ void gather_mean_128(const int* __restrict__ rowstart, const int* __restrict__ ebuf,
                                const unsigned* __restrict__ featb, unsigned* __restrict__ outb, int N) {
    int w = (blockIdx.x * blockDim.x + threadIdx.x) >> 6;
    int lane = threadIdx.x & 63;
    if (w >= N) return;
    int e0 = rowstart[w], e1 = rowstart[w + 1];
    float ax = 0.0f, ay = 0.0f;
    int i = e0;
    for (; i + 2 <= e1; i += 2) {           // 2-edge unroll for MLP
        int s0 = ebuf[i], s1 = ebuf[i + 1];
        unsigned v0 = featb[(size_t)s0 * 64 + lane];
        unsigned v1 = featb[(size_t)s1 * 64 + lane];
        ax += bf2f_lo(v0) + bf2f_lo(v1);
        ay += bf2f_hi(v0) + bf2f_hi(v1);
    }
    if (i < e1) {
        unsigned v = featb[(size_t)ebuf[i] * 64 + lane];
        ax += bf2f_lo(v); ay += bf2f_hi(v);
    }
    float inv = 1.0f / fmaxf((float)(e1 - e0), 1.0f);
    outb[(size_t)w * 64 + lane] = f2bf(ax * inv) | (f2bf(ay * inv) << 16);
}

// one wave per dst row; bf16 feat [N,512] -> bf16 mean [N,512]; fp32 accum
__global__ void gather_mean_512(const int* __restrict__ rowstart, const int* __restrict__ ebuf,
                                const unsigned short* __restrict__ featb,
                                unsigned short* __restrict__ outb, int N) {
    int w = (blockIdx.x * blockDim.x + threadIdx.x) >> 6;
    int lane = threadIdx.x & 63;
    if (w >= N) return;
    int e0 = rowstart[w], e1 = rowstart[w + 1];
    float a[8] = {0, 0, 0, 0, 0, 0, 0, 0};
    const uint4* base = (const uint4*)featb;     // 512 bf16/row = 64 uint4/row
    int i = e0;
    for (; i + 2 <= e1; i += 2) {           // 2-edge unroll for MLP
        int s0 = ebuf[i], s1 = ebuf[i + 1];
        uint4 v0 = base[(size_t)s0 * 64 + lane];
        uint4 v1 = base[(size_t)s1 * 64 + lane];
        a[0] += bf2f_lo(v0.x) + bf2f_lo(v1.x); a[1] += bf2f_hi(v0.x) + bf2f_hi(v1.x);
        a[2] += bf2f_lo(v0.y) + bf2f_lo(v1.y); a[3] += bf2f_hi(v0.y) + bf2f_hi(v1.y);
        a[4] += bf2f_lo(v0.z) + bf2f_lo(v1.z); a[5] += bf2f_hi(v0.z) + bf2f_hi(v1.z);
        a[6] += bf2f_lo(v0.w) + bf2f_lo(v1.w); a[7] += bf2f_hi(v0.w) + bf2f_hi(v1.w);
    }
    if (i < e1) {
        uint4 v = base[(size_t)ebuf[i] * 64 + lane];
        a[0] += bf2f_lo(v.x); a[1] += bf2f_hi(v.x);
        a[2] += bf2f_lo(v.y); a[3] += bf2f_hi(v.y);
        a[4] += bf2f_lo(v.z); a[5] += bf2f_hi(v.z);
        a[6] += bf2f_lo(v.w); a[7] += bf2f_hi(v.w);
    }
    float inv = 1.0f / fmaxf((float)(e1 - e0), 1.0f);
    uint4 o;
    o.x = f2bf(a[0] * inv) | (f2bf(a[1] * inv) << 16);
    o.y = f2bf(a[2] * inv) | (f2bf(a[3] * inv) << 16);
    o.z = f2bf(a[4] * inv) | (f2bf(a[5] * inv) << 16);
    o.w = f2bf(a[6] * inv) | (f2bf(a[7] * inv) << 16);
    ((uint4*)outb)[(size_t)w * 64 + lane] = o;
}

// ---------------- bf16 MFMA GEMM (dbuf global_load_lds) ----------------
// C = relu([A0b | A1b] @ Wb^T + b)
// mode 0: store C as bf16 to outb [N, C]
// mode 1: logit[row] += sum_col C[row,col] * Wo[col]
// Block 256 thr = 4 waves (2x2); tile 128x128; wave tile 64x64 (4x4 mfma);
// BK=32, double-buffered LDS, one barrier per iter.
// LDS layout per buffer: 16B chunk (row r, k-quad q) at byte (q*128+r)*16
// -> frag reads contiguous per quad (free 2-way aliasing only, 0 conflicts).
// REQUIRES K0 == K1, both multiples of 32.
__global__ __launch_bounds__(256) void gemm_mfma(
    const unsigned short* __restrict__ A0,   // [N, K0] bf16
    const unsigned short* __restrict__ A1,   // [N, K1] bf16, K1 == K0
    const unsigned short* __restrict__ W,    // [C, K0+K1] bf16 row-major
    const float* __restrict__ b,             // [C] fp32
    unsigned short* __restrict__ outb,       // [N, C] bf16 (mode 0)
    const float* __restrict__ Wo,            // [C] fp32    (mode 1)
    float* __restrict__ logit,               // [N] fp32    (mode 1)
    int N, int K0, int K1, int C, int mode)
{
    const int K = K0 + K1;
    const int S = K0;               // row stride of both A0 and A1
    __shared__ short As[2][4096];   // 8 KB per buffer
    __shared__ short Bs[2][4096];

    const int tid  = threadIdx.x;
    const int lane = tid & 63;
    const int wave = tid >> 6;
    const int wm = wave & 1, wn = wave >> 1;
    const int cl = lane & 15, quad = lane >> 4;
    const int row0 = blockIdx.y * 128;     // rowblk = slow grid dim
    const int col0 = blockIdx.x * 128;     // colblk = fast grid dim

    // staging: lane DMAs chunks s0 = wave*128+lane and s1 = s0+64,
    // chunk s = q*128 + r  (r = tile row, q = k-quad of 8 bf16)
    const int s0 = wave * 128 + lane;
    const int s1 = s0 + 64;
    const int r0 = s0 & 127, q0 = s0 >> 7;
    const int r1 = s1 & 127, q1 = s1 >> 7;
    // clamp OOB tile rows to N-1 (loaded garbage discarded by epilogue guard)
    const int ar0 = (row0 + r0 < N) ? row0 + r0 : N - 1;
    const int ar1 = (row0 + r1 < N) ? row0 + r1 : N - 1;
    const size_t aoff0 = (size_t)ar0 * S + q0 * 8;
    const size_t aoff1 = (size_t)ar1 * S + q1 * 8;
    const size_t boff0 = (size_t)(col0 + r0) * K + q0 * 8;
    const size_t boff1 = (size_t)(col0 + r1) * K + q1 * 8;
    const int ldso0 = (wave * 2 + 0) * 512;   // wave-uniform LDS base (shorts)
    const int ldso1 = (wave * 2 + 1) * 512;

    f32x4 acc[4][4];
    #pragma unroll
    for (int mt = 0; mt < 4; ++mt)
        #pragma unroll
        for (int nt = 0; nt < 4; ++nt)
            acc[mt][nt] = (f32x4){0.f, 0.f, 0.f, 0.f};

    // prologue: DMA tile 0 into buffer 0
    GLOAD_LDS16(A0 + aoff0, &As[0][ldso0]);
    GLOAD_LDS16(A0 + aoff1, &As[0][ldso1]);
    GLOAD_LDS16(W  + boff0, &Bs[0][ldso0]);
    GLOAD_LDS16(W  + boff1, &Bs[0][ldso1]);

    const int iters = K >> 5;
    for (int i = 0; i < iters; ++i) {
        const int cur = i & 1;
        // barrier drains tile i's DMA (vmcnt0) and fences tile i-1 frag reads
        __syncthreads();
        if (i + 1 < iters) {
            const int kn = (i + 1) << 5;
            const unsigned short* Ab = (kn < K0) ? (A0 + kn) : (A1 + (kn - K0));
            const unsigned short* Wb = W + kn;
            const int nb = cur ^ 1;
            GLOAD_LDS16(Ab + aoff0, &As[nb][ldso0]);
            GLOAD_LDS16(Ab + aoff1, &As[nb][ldso1]);
            GLOAD_LDS16(Wb + boff0, &Bs[nb][ldso0]);
            GLOAD_LDS16(Wb + boff1, &Bs[nb][ldso1]);
        }

        bf16x8 af[4], bfr[4];
        #pragma unroll
        for (int mt = 0; mt < 4; ++mt)
            af[mt] = *(const bf16x8*)&As[cur][quad * 1024 + (wm * 64 + mt * 16 + cl) * 8];
        #pragma unroll
        for (int nt = 0; nt < 4; ++nt)
            bfr[nt] = *(const bf16x8*)&Bs[cur][quad * 1024 + (wn * 64 + nt * 16 + cl) * 8];

        #pragma unroll
        for (int mt = 0; mt < 4; ++mt)
            #pragma unroll
            for (int nt = 0; nt < 4; ++nt)
                acc[mt][nt] = __builtin_amdgcn_mfma_f32_16x16x32_bf16(
                    af[mt], bfr[nt], acc[mt][nt], 0, 0, 0);
    }

    if (mode == 0) {
        #pragma unroll
        for (int nt = 0; nt < 4; ++nt) {
            const int colb = col0 + wn * 64 + nt * 16 + cl;
            const float bb = b[colb];
            #pragma unroll
            for (int mt = 0; mt < 4; ++mt) {
                #pragma unroll
                for (int r = 0; r < 4; ++r) {
                    int row = row0 + wm * 64 + mt * 16 + quad * 4 + r;
                    if (row < N)
                        outb[(size_t)row * C + colb] =
                            (unsigned short)f2bf(fmaxf(acc[mt][nt][r] + bb, 0.0f));
                }
            }
        }
    } else {
        float bv[4], wv2[4];
        #pragma unroll
        for (int nt = 0; nt < 4; ++nt) {
            const int colb = col0 + wn * 64 + nt * 16 + cl;
            bv[nt] = b[colb];
            wv2[nt] = Wo[colb];
        }
        #pragma unroll
        for (int mt = 0; mt < 4; ++mt) {
            #pragma unroll
            for (int r = 0; r < 4; ++r) {
                float s = 0.0f;
                #pragma unroll
                for (int nt = 0; nt < 4; ++nt)
                    s += fmaxf(acc[mt][nt][r] + bv[nt], 0.0f) * wv2[nt];
                s += __shfl_xor(s, 1);
                s += __shfl_xor(s, 2);
                s += __shfl_xor(s, 4);
                s += __shfl_xor(s, 8);
                int row = row0 + wm * 64 + mt * 16 + quad * 4 + r;
                if (cl == 0 && row < N) atomicAdd(&logit[row], s);
            }
        }
    }
}

__global__ void head_kernel(const float* __restrict__ logit, const float* __restrict__ bo,
                            float* __restrict__ out, int N) {
    int i = blockIdx.x * 256 + threadIdx.x;
    if (i < N) out[i] = 1.0f / (1.0f + expf(-(logit[i] + bo[0])));
}

extern "C" void kernel_launch(void* const* d_in, const int* in_sizes, int n_in,
                              void* d_out, int out_size, void* d_ws, size_t ws_size,
                              hipStream_t stream) {
    const float* x  = (const float*)d_in[0];
    const int*   ei = (const int*)d_in[1];
    const float* W1 = (const float*)d_in[2];
    const float* b1 = (const float*)d_in[3];
    const float* W2 = (const float*)d_in[4];
    const float* b2 = (const float*)d_in[5];
    const float* Wo = (const float*)d_in[6];
    const float* bo = (const float*)d_in[7];
    float* out = (float*)d_out;

    const int N = in_sizes[0] / 128;   // 50000
    const int E = in_sizes[1] / 2;     // 400000
    const int* src = ei;
    const int* dst = ei + E;

    char* ws = (char*)d_ws;
    size_t off = 0;
    auto alloc = [&](size_t bytes) {
        void* p = ws + off;
        off += (bytes + 255) & ~(size_t)255;
        return p;
    };
    int* deg      = (int*)alloc((size_t)N * 4);
    int* rowstart = (int*)alloc((size_t)(N + 1) * 4);
    int* cursor   = (int*)alloc((size_t)N * 4);
    int* partial  = (int*)alloc((size_t)64 * 4);
    int* ebuf     = (int*)alloc((size_t)E * 4);
    float* logit  = (float*)alloc((size_t)N * 4);
    unsigned short* xb  = (unsigned short*)alloc((size_t)N * 128 * 2);
    unsigned short* W1b = (unsigned short*)alloc((size_t)512 * 256 * 2);
    unsigned short* W2b = (unsigned short*)alloc((size_t)512 * 1024 * 2);
    unsigned short* n1b = (unsigned short*)alloc((size_t)N * 128 * 2);
    unsigned short* h1b = (unsigned short*)alloc((size_t)N * 512 * 2);
    unsigned short* n2b = (unsigned short*)alloc((size_t)N * 512 * 2);
    (void)ws_size; (void)n_in; (void)out_size;

    hipMemsetAsync(deg,   0, (size_t)N * 4, stream);
    hipMemsetAsync(logit, 0, (size_t)N * 4, stream);

    // conversions
    cvt_bf16_kernel<<<ceil_div(N * 128 / 4, 256), 256, 0, stream>>>(x, xb, N * 128 / 4);
    cvt_bf16_kernel<<<ceil_div(512 * 256 / 4, 256), 256, 0, stream>>>(W1, W1b, 512 * 256 / 4);
    cvt_bf16_kernel<<<ceil_div(512 * 1024 / 4, 256), 256, 0, stream>>>(W2, W2b, 512 * 1024 / 4);

    // CSR build (hierarchical scan)
    const int P = ceil_div(N, 1024);   // 49
    hist_kernel<<<ceil_div(E, 256), 256, 0, stream>>>(dst, deg, E);
    chunk_reduce<<<P, 256, 0, stream>>>(deg, partial, N);
    partial_scan<<<1, 64, 0, stream>>>(partial, rowstart + N, P);
    chunk_scan<<<P, 256, 0, stream>>>(deg, partial, rowstart, cursor, N);
    bucket_kernel<<<ceil_div(E, 256), 256, 0, stream>>>(src, dst, cursor, ebuf, E);

    dim3 gg(512 / 128, ceil_div(N, 128));   // (colblk fast, rowblk slow)

    // layer 1
    gather_mean_128<<<ceil_div(N * 64, 256), 256, 0, stream>>>(rowstart, ebuf,
                                                               (const unsigned*)xb, (unsigned*)n1b, N);
    gemm_mfma<<<gg, 256, 0, stream>>>(xb, n1b, W1b, b1, h1b, nullptr, nullptr,
                                      N, 128, 128, 512, 0);

    // layer 2 + fused head
    gather_mean_512<<<ceil_div(N * 64, 256), 256, 0, stream>>>(rowstart, ebuf, h1b, n2b, N);
    gemm_mfma<<<gg, 256, 0, stream>>>(h1b, n2b, W2b, b2, nullptr, Wo, logit,
                                      N, 512, 512, 512, 1);

    head_kernel<<<ceil_div(N, 256), 256, 0, stream>>>(logit, bo, out, N);
}

// Round 9
// 364.720 us; speedup vs baseline: 1.2224x; 1.1506x over previous
//
#include <hip/hip_runtime.h>
#include <math.h>

// ---------------------------------------------------------------------------
// GraphSAGE fraud detector. CSR-gather aggregation + bf16 MFMA GEMMs.
// R9: coalesced DMA staging. R7/R8 had consecutive lanes loading consecutive
// ROWS (stride 2KB): each global_load_lds_dwordx4 = 64 scattered 16B
// transactions -> latency wall (138us, MfmaUtil 15%). Now lane=4r+j loads
// row r's j-th 16B of its 64B K-slice: 16 contiguous 64B segments per
// instruction (4x fewer transactions). LDS = row-major [128][32] tile;
// frag reads row*64B+quad*16B are conflict-free (8 hits/bank over 8-clock
// b128). Keeps R8's dbuf one-barrier loop. Gathers: 4-edge unroll.
// MFMA 16x16x32 bf16: A-frag A[m=lane&15][k=quad*8+j]; C/D col=lane&15,
// row=quad*4+reg (m89/m97-verified layouts).
// ---------------------------------------------------------------------------

typedef __attribute__((ext_vector_type(8))) short bf16x8;   // 8 bf16, 4 VGPRs
typedef __attribute__((ext_vector_type(4))) float f32x4;

static inline int ceil_div(int a, int b) { return (a + b - 1) / b; }

__device__ inline float bf2f_lo(unsigned u) { return __builtin_bit_cast(float, u << 16); }
__device__ inline float bf2f_hi(unsigned u) { return __builtin_bit_cast(float, u & 0xffff0000u); }
__device__ inline unsigned f2bf(float f) {   // RNE round to bf16, bits in low 16
    unsigned u = __builtin_bit_cast(unsigned, f);
    u += 0x7fffu + ((u >> 16) & 1u);
    return u >> 16;
}

// async global->LDS, 16 B per lane; LDS dest = wave-uniform base + lane*16
#define GLOAD_LDS16(gp, lp)                                                   \
    __builtin_amdgcn_global_load_lds(                                         \
        (__attribute__((address_space(1))) void*)(gp),                        \
        (__attribute__((address_space(3))) void*)(lp), 16, 0, 0)

// ---------------- CSR build ----------------

__global__ void hist_kernel(const int* __restrict__ dst, int* __restrict__ deg, int E) {
    int e = blockIdx.x * 256 + threadIdx.x;
    if (e < E) atomicAdd(&deg[dst[e]], 1);
}

// per-1024-chunk sums
__global__ __launch_bounds__(256) void chunk_reduce(const int* __restrict__ deg,
                                                    int* __restrict__ partial, int N) {
    int base = blockIdx.x * 1024;
    int s = 0;
    for (int i = threadIdx.x; i < 1024; i += 256) {
        int idx = base + i;
        if (idx < N) s += deg[idx];
    }
    #pragma unroll
    for (int off = 32; off; off >>= 1) s += __shfl_down(s, off);
    __shared__ int ws[4];
    if ((threadIdx.x & 63) == 0) ws[threadIdx.x >> 6] = s;
    __syncthreads();
    if (threadIdx.x == 0) partial[blockIdx.x] = ws[0] + ws[1] + ws[2] + ws[3];
}

// exclusive scan of P<=64 partials (one wave); writes rowstart[N]=total
__global__ void partial_scan(int* __restrict__ partial, int* __restrict__ rowstartN, int P) {
    int lane = threadIdx.x;
    int v = (lane < P) ? partial[lane] : 0;
    int incl = v;
    #pragma unroll
    for (int off = 1; off < 64; off <<= 1) {
        int t = __shfl_up(incl, off);
        if (lane >= off) incl += t;
    }
    if (lane < P) partial[lane] = incl - v;
    if (lane == 63) *rowstartN = incl;
}

// per-chunk exclusive scan + global offset; writes rowstart and cursor
__global__ __launch_bounds__(256) void chunk_scan(const int* __restrict__ deg,
                                                  const int* __restrict__ partial,
                                                  int* __restrict__ rowstart,
                                                  int* __restrict__ cursor, int N) {
    int base = blockIdx.x * 1024 + threadIdx.x * 4;
    int v[4];
    #pragma unroll
    for (int j = 0; j < 4; ++j) {
        int i = base + j;
        v[j] = (i < N) ? deg[i] : 0;
    }
    int mysum = v[0] + v[1] + v[2] + v[3];
    int incl = mysum;
    int lane = threadIdx.x & 63, wave = threadIdx.x >> 6;
    #pragma unroll
    for (int off = 1; off < 64; off <<= 1) {
        int t = __shfl_up(incl, off);
        if (lane >= off) incl += t;
    }
    __shared__ int ws[4];
    if (lane == 63) ws[wave] = incl;
    __syncthreads();
    int run = partial[blockIdx.x] + incl - mysum;
    for (int w = 0; w < wave; ++w) run += ws[w];
    #pragma unroll
    for (int j = 0; j < 4; ++j) {
        int i = base + j;
        if (i < N) { rowstart[i] = run; cursor[i] = run; }
        run += v[j];
    }
}

__global__ void bucket_kernel(const int* __restrict__ src, const int* __restrict__ dst,
                              int* __restrict__ cursor, int* __restrict__ ebuf, int E) {
    int e = blockIdx.x * 256 + threadIdx.x;
    if (e < E) {
        int pos = atomicAdd(&cursor[dst[e]], 1);
        ebuf[pos] = src[e];
    }
}

// ---------------- dtype conversion ----------------

__global__ void cvt_bf16_kernel(const float* __restrict__ in, unsigned short* __restrict__ out, int n4) {
    int i = blockIdx.x * 256 + threadIdx.x;
    if (i < n4) {
        float4 v = ((const float4*)in)[i];
        ushort4 o;
        o.x = (unsigned short)f2bf(v.x);
        o.y = (unsigned short)f2bf(v.y);
        o.z = (unsigned short)f2bf(v.z);
        o.w = (unsigned short)f2bf(v.w);
        ((ushort4*)out)[i] = o;
    }
}

// ---------------- gather means ----------------

// one wave per dst row; bf16 xb [N,128] -> bf16 mean [N,128]; fp32 accum
__global__ void gather_mean_128(const int* __restrict__ rowstart, const int* __restrict__ ebuf,
                                const unsigned* __restrict__ featb, unsigned* __restrict__ outb, int N) {
    int w = (blockIdx.x * blockDim.x + threadIdx.x) >> 6;
    int lane = threadIdx.x & 63;
    if (w >= N) return;
    int e0 = rowstart[w], e1 = rowstart[w + 1];
    float ax = 0.0f, ay = 0.0f;
    int i = e0;
    for (; i + 4 <= e1; i += 4) {           // 4-edge unroll for MLP
        unsigned v0 = featb[(size_t)ebuf[i]     * 64 + lane];
        unsigned v1 = featb[(size_t)ebuf[i + 1] * 64 + lane];
        unsigned v2 = featb[(size_t)ebuf[i + 2] * 64 + lane];
        unsigned v3 = featb[(size_t)ebuf[i + 3] * 64 + lane];
        ax += bf2f_lo(v0) + bf2f_lo(v1) + bf2f_lo(v2) + bf2f_lo(v3);
        ay += bf2f_hi(v0) + bf2f_hi(v1) + bf2f_hi(v2) + bf2f_hi(v3);
    }
    for (; i < e1; ++i) {
        unsigned v = featb[(size_t)ebuf[i] * 64 + lane];
        ax += bf2f_lo(v); ay += bf2f_hi(v);
    }
    float inv = 1.0f / fmaxf((float)(e1 - e0), 1.0f);
    outb[(size_t)w * 64 + lane] = f2bf(ax * inv) | (f2bf(ay * inv) << 16);
}

// one wave per dst row; bf16 feat [N,512] -> bf16 mean [N,512]; fp32 accum
__global__ void gather_mean_512(const int* __restrict__ rowstart, const int* __restrict__ ebuf,
                                const unsigned short* __restrict__ featb,
                                unsigned short* __restrict__ outb, int N) {
    int w = (blockIdx.x * blockDim.x + threadIdx.x) >> 6;
    int lane = threadIdx.x & 63;
    if (w >= N) return;
    int e0 = rowstart[w], e1 = rowstart[w + 1];
    float a[8] = {0, 0, 0, 0, 0, 0, 0, 0};
    const uint4* base = (const uint4*)featb;     // 512 bf16/row = 64 uint4/row
    int i = e0;
    for (; i + 4 <= e1; i += 4) {           // 4-edge unroll for MLP
        uint4 v0 = base[(size_t)ebuf[i]     * 64 + lane];
        uint4 v1 = base[(size_t)ebuf[i + 1] * 64 + lane];
        uint4 v2 = base[(size_t)ebuf[i + 2] * 64 + lane];
        uint4 v3 = base[(size_t)ebuf[i + 3] * 64 + lane];
        a[0] += bf2f_lo(v0.x) + bf2f_lo(v1.x) + bf2f_lo(v2.x) + bf2f_lo(v3.x);
        a[1] += bf2f_hi(v0.x) + bf2f_hi(v1.x) + bf2f_hi(v2.x) + bf2f_hi(v3.x);
        a[2] += bf2f_lo(v0.y) + bf2f_lo(v1.y) + bf2f_lo(v2.y) + bf2f_lo(v3.y);
        a[3] += bf2f_hi(v0.y) + bf2f_hi(v1.y) + bf2f_hi(v2.y) + bf2f_hi(v3.y);
        a[4] += bf2f_lo(v0.z) + bf2f_lo(v1.z) + bf2f_lo(v2.z) + bf2f_lo(v3.z);
        a[5] += bf2f_hi(v0.z) + bf2f_hi(v1.z) + bf2f_hi(v2.z) + bf2f_hi(v3.z);
        a[6] += bf2f_lo(v0.w) + bf2f_lo(v1.w) + bf2f_lo(v2.w) + bf2f_lo(v3.w);
        a[7] += bf2f_hi(v0.w) + bf2f_hi(v1.w) + bf2f_hi(v2.w) + bf2f_hi(v3.w);
    }
    for (; i < e1; ++i) {
        uint4 v = base[(size_t)ebuf[i] * 64 + lane];
        a[0] += bf2f_lo(v.x); a[1] += bf2f_hi(v.x);
        a[2] += bf2f_lo(v.y); a[3] += bf2f_hi(v.y);
        a[4] += bf2f_lo(v.z); a[5] += bf2f_hi(v.z);
        a[6] += bf2f_lo(v.w); a[7] += bf2f_hi(v.w);
    }
    float inv = 1.0f / fmaxf((float)(e1 - e0), 1.0f);
    uint4 o;
    o.x = f2bf(a[0] * inv) | (f2bf(a[1] * inv) << 16);
    o.y = f2bf(a[2] * inv) | (f2bf(a[3] * inv) << 16);
    o.z = f2bf(a[4] * inv) | (f2bf(a[5] * inv) << 16);
    o.w = f2bf(a[6] * inv) | (f2bf(a[7] * inv) << 16);
    ((uint4*)outb)[(size_t)w * 64 + lane] = o;
}

// ---------------- bf16 MFMA GEMM (coalesced dbuf DMA) ----------------
// C = relu([A0b | A1b] @ Wb^T + b)
// mode 0: store C as bf16 to outb [N, C]
// mode 1: logit[row] += sum_col C[row,col] * Wo[col]
// Block 256 thr = 4 waves (2x2); tile 128x128; wave tile 64x64 (4x4 mfma);
// BK=32, double-buffered LDS, one barrier per iter.
// Staging: lane = 4r+j loads row (wave*32 [+16] + r)'s j-th 16B of its 64B
// K-slice -> 16 contiguous 64B segments per wave-instruction.
// LDS per buffer: row-major [128][32] bf16 tile (8 KB).
// REQUIRES K0 == K1, both multiples of 32.
__global__ __launch_bounds__(256) void gemm_mfma(
    const unsigned short* __restrict__ A0,   // [N, K0] bf16
    const unsigned short* __restrict__ A1,   // [N, K1] bf16, K1 == K0
    const unsigned short* __restrict__ W,    // [C, K0+K1] bf16 row-major
    const float* __restrict__ b,             // [C] fp32
    unsigned short* __restrict__ outb,       // [N, C] bf16 (mode 0)
    const float* __restrict__ Wo,            // [C] fp32    (mode 1)
    float* __restrict__ logit,               // [N] fp32    (mode 1)
    int N, int K0, int K1, int C, int mode)
{
    const int K = K0 + K1;
    const int S = K0;               // row stride of both A0 and A1
    __shared__ short As[2][4096];   // [128][32] per buffer, 8 KB
    __shared__ short Bs[2][4096];

    const int tid  = threadIdx.x;
    const int lane = tid & 63;
    const int wave = tid >> 6;
    const int wm = wave & 1, wn = wave >> 1;
    const int cl = lane & 15, quad = lane >> 4;
    const int row0 = blockIdx.y * 128;     // rowblk = slow grid dim
    const int col0 = blockIdx.x * 128;     // colblk = fast grid dim

    // staging: lane = 4r+j; wave w, load i covers tile rows w*32+i*16 .. +16
    const int r = lane >> 2;        // 0..15
    const int j = lane & 3;         // 16B chunk within the row's 64B K-slice
    const int trow0 = wave * 32 + r;
    const int trow1 = trow0 + 16;
    // clamp OOB tile rows to N-1 (loaded garbage discarded by epilogue guard)
    const int ar0 = (row0 + trow0 < N) ? row0 + trow0 : N - 1;
    const int ar1 = (row0 + trow1 < N) ? row0 + trow1 : N - 1;
    const size_t aoff0 = (size_t)ar0 * S + j * 8;
    const size_t aoff1 = (size_t)ar1 * S + j * 8;
    const size_t boff0 = (size_t)(col0 + trow0) * K + j * 8;
    const size_t boff1 = (size_t)(col0 + trow1) * K + j * 8;
    const int lds0 = (wave * 32) * 32;        // shorts; wave-uniform
    const int lds1 = (wave * 32 + 16) * 32;

    f32x4 acc[4][4];
    #pragma unroll
    for (int mt = 0; mt < 4; ++mt)
        #pragma unroll
        for (int nt = 0; nt < 4; ++nt)
            acc[mt][nt] = (f32x4){0.f, 0.f, 0.f, 0.f};

    // prologue: DMA tile 0 into buffer 0
    GLOAD_LDS16(A0 + aoff0, &As[0][lds0]);
    GLOAD_LDS16(A0 + aoff1, &As[0][lds1]);
    GLOAD_LDS16(W  + boff0, &Bs[0][lds0]);
    GLOAD_LDS16(W  + boff1, &Bs[0][lds1]);

    const int iters = K >> 5;
    for (int i = 0; i < iters; ++i) {
        const int cur = i & 1;
        // barrier drains tile i's DMA (vmcnt0) and fences tile i-1 frag reads
        __syncthreads();
        if (i + 1 < iters) {
            const int kn = (i + 1) << 5;
            const unsigned short* Ab = (kn < K0) ? (A0 + kn) : (A1 + (kn - K0));
            const unsigned short* Wb = W + kn;
            const int nb = cur ^ 1;
            GLOAD_LDS16(Ab + aoff0, &As[nb][lds0]);
            GLOAD_LDS16(Ab + aoff1, &As[nb][lds1]);
            GLOAD_LDS16(Wb + boff0, &Bs[nb][lds0]);
            GLOAD_LDS16(Wb + boff1, &Bs[nb][lds1]);
        }

        bf16x8 af[4], bfr[4];
        #pragma unroll
        for (int mt = 0; mt < 4; ++mt)
            af[mt] = *(const bf16x8*)&As[cur][(wm * 64 + mt * 16 + cl) * 32 + quad * 8];
        #pragma unroll
        for (int nt = 0; nt < 4; ++nt)
            bfr[nt] = *(const bf16x8*)&Bs[cur][(wn * 64 + nt * 16 + cl) * 32 + quad * 8];

        #pragma unroll
        for (int mt = 0; mt < 4; ++mt)
            #pragma unroll
            for (int nt = 0; nt < 4; ++nt)
                acc[mt][nt] = __builtin_amdgcn_mfma_f32_16x16x32_bf16(
                    af[mt], bfr[nt], acc[mt][nt], 0, 0, 0);
    }

    if (mode == 0) {
        #pragma unroll
        for (int nt = 0; nt < 4; ++nt) {
            const int colb = col0 + wn * 64 + nt * 16 + cl;
            const float bb = b[colb];
            #pragma unroll
            for (int mt = 0; mt < 4; ++mt) {
                #pragma unroll
                for (int rr = 0; rr < 4; ++rr) {
                    int row = row0 + wm * 64 + mt * 16 + quad * 4 + rr;
                    if (row < N)
                        outb[(size_t)row * C + colb] =
                            (unsigned short)f2bf(fmaxf(acc[mt][nt][rr] + bb, 0.0f));
                }
            }
        }
    } else {
        float bv[4], wv2[4];
        #pragma unroll
        for (int nt = 0; nt < 4; ++nt) {
            const int colb = col0 + wn * 64 + nt * 16 + cl;
            bv[nt] = b[colb];
            wv2[nt] = Wo[colb];
        }
        #pragma unroll
        for (int mt = 0; mt < 4; ++mt) {
            #pragma unroll
            for (int rr = 0; rr < 4; ++rr) {
                float s = 0.0f;
                #pragma unroll
                for (int nt = 0; nt < 4; ++nt)
                    s += fmaxf(acc[mt][nt][rr] + bv[nt], 0.0f) * wv2[nt];
                s += __shfl_xor(s, 1);
                s += __shfl_xor(s, 2);
                s += __shfl_xor(s, 4);
                s += __shfl_xor(s, 8);
                int row = row0 + wm * 64 + mt * 16 + quad * 4 + rr;
                if (cl == 0 && row < N) atomicAdd(&logit[row], s);
            }
        }
    }
}

__global__ void head_kernel(const float* __restrict__ logit, const float* __restrict__ bo,
                            float* __restrict__ out, int N) {
    int i = blockIdx.x * 256 + threadIdx.x;
    if (i < N) out[i] = 1.0f / (1.0f + expf(-(logit[i] + bo[0])));
}

extern "C" void kernel_launch(void* const* d_in, const int* in_sizes, int n_in,
                              void* d_out, int out_size, void* d_ws, size_t ws_size,
                              hipStream_t stream) {
    const float* x  = (const float*)d_in[0];
    const int*   ei = (const int*)d_in[1];
    const float* W1 = (const float*)d_in[2];
    const float* b1 = (const float*)d_in[3];
    const float* W2 = (const float*)d_in[4];
    const float* b2 = (const float*)d_in[5];
    const float* Wo = (const float*)d_in[6];
    const float* bo = (const float*)d_in[7];
    float* out = (float*)d_out;

    const int N = in_sizes[0] / 128;   // 50000
    const int E = in_sizes[1] / 2;     // 400000
    const int* src = ei;
    const int* dst = ei + E;

    char* ws = (char*)d_ws;
    size_t off = 0;
    auto alloc = [&](size_t bytes) {
        void* p = ws + off;
        off += (bytes + 255) & ~(size_t)255;
        return p;
    };
    int* deg      = (int*)alloc((size_t)N * 4);
    int* rowstart = (int*)alloc((size_t)(N + 1) * 4);
    int* cursor   = (int*)alloc((size_t)N * 4);
    int* partial  = (int*)alloc((size_t)64 * 4);
    int* ebuf     = (int*)alloc((size_t)E * 4);
    float* logit  = (float*)alloc((size_t)N * 4);
    unsigned short* xb  = (unsigned short*)alloc((size_t)N * 128 * 2);
    unsigned short* W1b = (unsigned short*)alloc((size_t)512 * 256 * 2);
    unsigned short* W2b = (unsigned short*)alloc((size_t)512 * 1024 * 2);
    unsigned short* n1b = (unsigned short*)alloc((size_t)N * 128 * 2);
    unsigned short* h1b = (unsigned short*)alloc((size_t)N * 512 * 2);
    unsigned short* n2b = (unsigned short*)alloc((size_t)N * 512 * 2);
    (void)ws_size; (void)n_in; (void)out_size;

    hipMemsetAsync(deg,   0, (size_t)N * 4, stream);
    hipMemsetAsync(logit, 0, (size_t)N * 4, stream);

    // conversions
    cvt_bf16_kernel<<<ceil_div(N * 128 / 4, 256), 256, 0, stream>>>(x, xb, N * 128 / 4);
    cvt_bf16_kernel<<<ceil_div(512 * 256 / 4, 256), 256, 0, stream>>>(W1, W1b, 512 * 256 / 4);
    cvt_bf16_kernel<<<ceil_div(512 * 1024 / 4, 256), 256, 0, stream>>>(W2, W2b, 512 * 1024 / 4);

    // CSR build (hierarchical scan)
    const int P = ceil_div(N, 1024);   // 49
    hist_kernel<<<ceil_div(E, 256), 256, 0, stream>>>(dst, deg, E);
    chunk_reduce<<<P, 256, 0, stream>>>(deg, partial, N);
    partial_scan<<<1, 64, 0, stream>>>(partial, rowstart + N, P);
    chunk_scan<<<P, 256, 0, stream>>>(deg, partial, rowstart, cursor, N);
    bucket_kernel<<<ceil_div(E, 256), 256, 0, stream>>>(src, dst, cursor, ebuf, E);

    dim3 gg(512 / 128, ceil_div(N, 128));   // (colblk fast, rowblk slow)

    // layer 1
    gather_mean_128<<<ceil_div(N * 64, 256), 256, 0, stream>>>(rowstart, ebuf,
                                                               (const unsigned*)xb, (unsigned*)n1b, N);
    gemm_mfma<<<gg, 256, 0, stream>>>(xb, n1b, W1b, b1, h1b, nullptr, nullptr,
                                      N, 128, 128, 512, 0);

    // layer 2 + fused head
    gather_mean_512<<<ceil_div(N * 64, 256), 256, 0, stream>>>(rowstart, ebuf, h1b, n2b, N);
    gemm_mfma<<<gg, 256, 0, stream>>>(h1b, n2b, W2b, b2, nullptr, Wo, logit,
                                      N, 512, 512, 512, 1);

    head_kernel<<<ceil_div(N, 256), 256, 0, stream>>>(logit, bo, out, N);
}

// Round 10
// 352.797 us; speedup vs baseline: 1.2637x; 1.0338x over previous
//
#include <hip/hip_runtime.h>
#include <math.h>

// ---------------------------------------------------------------------------
// GraphSAGE fraud detector. CSR-gather aggregation + bf16 MFMA GEMMs.
// R10: XCD-aware swizzle for the GEMM grid. R9 showed gemm2 fetch-limited:
// FETCH = 2x A (202 MB) because the 4 column-siblings of each A row-tile
// run on different XCDs (non-coherent L2s). 1D grid, id -> xcd=id&7,
// col=(id>>3)&3, row=(id>>5)*8+xcd: all 4 col-siblings land on ONE XCD,
// A fetched into its L2 once. Working set 16 row-tiles x 256 KB = 4 MB = L2.
// Keeps R9's coalesced dbuf DMA staging (lane=4r+j, 64B row slices).
// MFMA 16x16x32 bf16: A-frag A[m=lane&15][k=quad*8+j]; C/D col=lane&15,
// row=quad*4+reg (m89/m97-verified layouts).
// ---------------------------------------------------------------------------

typedef __attribute__((ext_vector_type(8))) short bf16x8;   // 8 bf16, 4 VGPRs
typedef __attribute__((ext_vector_type(4))) float f32x4;

static inline int ceil_div(int a, int b) { return (a + b - 1) / b; }

__device__ inline float bf2f_lo(unsigned u) { return __builtin_bit_cast(float, u << 16); }
__device__ inline float bf2f_hi(unsigned u) { return __builtin_bit_cast(float, u & 0xffff0000u); }
__device__ inline unsigned f2bf(float f) {   // RNE round to bf16, bits in low 16
    unsigned u = __builtin_bit_cast(unsigned, f);
    u += 0x7fffu + ((u >> 16) & 1u);
    return u >> 16;
}

// async global->LDS, 16 B per lane; LDS dest = wave-uniform base + lane*16
#define GLOAD_LDS16(gp, lp)                                                   \
    __builtin_amdgcn_global_load_lds(                                         \
        (__attribute__((address_space(1))) void*)(gp),                        \
        (__attribute__((address_space(3))) void*)(lp), 16, 0, 0)

// ---------------- CSR build ----------------

__global__ void hist_kernel(const int* __restrict__ dst, int* __restrict__ deg, int E) {
    int e = blockIdx.x * 256 + threadIdx.x;
    if (e < E) atomicAdd(&deg[dst[e]], 1);
}

// per-1024-chunk sums
__global__ __launch_bounds__(256) void chunk_reduce(const int* __restrict__ deg,
                                                    int* __restrict__ partial, int N) {
    int base = blockIdx.x * 1024;
    int s = 0;
    for (int i = threadIdx.x; i < 1024; i += 256) {
        int idx = base + i;
        if (idx < N) s += deg[idx];
    }
    #pragma unroll
    for (int off = 32; off; off >>= 1) s += __shfl_down(s, off);
    __shared__ int ws[4];
    if ((threadIdx.x & 63) == 0) ws[threadIdx.x >> 6] = s;
    __syncthreads();
    if (threadIdx.x == 0) partial[blockIdx.x] = ws[0] + ws[1] + ws[2] + ws[3];
}

// exclusive scan of P<=64 partials (one wave); writes rowstart[N]=total
__global__ void partial_scan(int* __restrict__ partial, int* __restrict__ rowstartN, int P) {
    int lane = threadIdx.x;
    int v = (lane < P) ? partial[lane] : 0;
    int incl = v;
    #pragma unroll
    for (int off = 1; off < 64; off <<= 1) {
        int t = __shfl_up(incl, off);
        if (lane >= off) incl += t;
    }
    if (lane < P) partial[lane] = incl - v;
    if (lane == 63) *rowstartN = incl;
}

// per-chunk exclusive scan + global offset; writes rowstart and cursor
__global__ __launch_bounds__(256) void chunk_scan(const int* __restrict__ deg,
                                                  const int* __restrict__ partial,
                                                  int* __restrict__ rowstart,
                                                  int* __restrict__ cursor, int N) {
    int base = blockIdx.x * 1024 + threadIdx.x * 4;
    int v[4];
    #pragma unroll
    for (int j = 0; j < 4; ++j) {
        int i = base + j;
        v[j] = (i < N) ? deg[i] : 0;
    }
    int mysum = v[0] + v[1] + v[2] + v[3];
    int incl = mysum;
    int lane = threadIdx.x & 63, wave = threadIdx.x >> 6;
    #pragma unroll
    for (int off = 1; off < 64; off <<= 1) {
        int t = __shfl_up(incl, off);
        if (lane >= off) incl += t;
    }
    __shared__ int ws[4];
    if (lane == 63) ws[wave] = incl;
    __syncthreads();
    int run = partial[blockIdx.x] + incl - mysum;
    for (int w = 0; w < wave; ++w) run += ws[w];
    #pragma unroll
    for (int j = 0; j < 4; ++j) {
        int i = base + j;
        if (i < N) { rowstart[i] = run; cursor[i] = run; }
        run += v[j];
    }
}

__global__ void bucket_kernel(const int* __restrict__ src, const int* __restrict__ dst,
                              int* __restrict__ cursor, int* __restrict__ ebuf, int E) {
    int e = blockIdx.x * 256 + threadIdx.x;
    if (e < E) {
        int pos = atomicAdd(&cursor[dst[e]], 1);
        ebuf[pos] = src[e];
    }
}

// ---------------- dtype conversion ----------------

__global__ void cvt_bf16_kernel(const float* __restrict__ in, unsigned short* __restrict__ out, int n4) {
    int i = blockIdx.x * 256 + threadIdx.x;
    if (i < n4) {
        float4 v = ((const float4*)in)[i];
        ushort4 o;
        o.x = (unsigned short)f2bf(v.x);
        o.y = (unsigned short)f2bf(v.y);
        o.z = (unsigned short)f2bf(v.z);
        o.w = (unsigned short)f2bf(v.w);
        ((ushort4*)out)[i] = o;
    }
}

// ---------------- gather means ----------------

// one wave per dst row; bf16 xb [N,128] -> bf16 mean [N,128]; fp32 accum
__global__ void gather_mean_128(const int* __restrict__ rowstart, const int* __restrict__ ebuf,
                                const unsigned* __restrict__ featb, unsigned* __restrict__ outb, int N) {
    int w = (blockIdx.x * blockDim.x + threadIdx.x) >> 6;
    int lane = threadIdx.x & 63;
    if (w >= N) return;
    int e0 = rowstart[w], e1 = rowstart[w + 1];
    float ax = 0.0f, ay = 0.0f;
    int i = e0;
    for (; i + 4 <= e1; i += 4) {           // 4-edge unroll for MLP
        unsigned v0 = featb[(size_t)ebuf[i]     * 64 + lane];
        unsigned v1 = featb[(size_t)ebuf[i + 1] * 64 + lane];
        unsigned v2 = featb[(size_t)ebuf[i + 2] * 64 + lane];
        unsigned v3 = featb[(size_t)ebuf[i + 3] * 64 + lane];
        ax += bf2f_lo(v0) + bf2f_lo(v1) + bf2f_lo(v2) + bf2f_lo(v3);
        ay += bf2f_hi(v0) + bf2f_hi(v1) + bf2f_hi(v2) + bf2f_hi(v3);
    }
    for (; i < e1; ++i) {
        unsigned v = featb[(size_t)ebuf[i] * 64 + lane];
        ax += bf2f_lo(v); ay += bf2f_hi(v);
    }
    float inv = 1.0f / fmaxf((float)(e1 - e0), 1.0f);
    outb[(size_t)w * 64 + lane] = f2bf(ax * inv) | (f2bf(ay * inv) << 16);
}

// one wave per dst row; bf16 feat [N,512] -> bf16 mean [N,512]; fp32 accum
__global__ void gather_mean_512(const int* __restrict__ rowstart, const int* __restrict__ ebuf,
                                const unsigned short* __restrict__ featb,
                                unsigned short* __restrict__ outb, int N) {
    int w = (blockIdx.x * blockDim.x + threadIdx.x) >> 6;
    int lane = threadIdx.x & 63;
    if (w >= N) return;
    int e0 = rowstart[w], e1 = rowstart[w + 1];
    float a[8] = {0, 0, 0, 0, 0, 0, 0, 0};
    const uint4* base = (const uint4*)featb;     // 512 bf16/row = 64 uint4/row
    int i = e0;
    for (; i + 4 <= e1; i += 4) {           // 4-edge unroll for MLP
        uint4 v0 = base[(size_t)ebuf[i]     * 64 + lane];
        uint4 v1 = base[(size_t)ebuf[i + 1] * 64 + lane];
        uint4 v2 = base[(size_t)ebuf[i + 2] * 64 + lane];
        uint4 v3 = base[(size_t)ebuf[i + 3] * 64 + lane];
        a[0] += bf2f_lo(v0.x) + bf2f_lo(v1.x) + bf2f_lo(v2.x) + bf2f_lo(v3.x);
        a[1] += bf2f_hi(v0.x) + bf2f_hi(v1.x) + bf2f_hi(v2.x) + bf2f_hi(v3.x);
        a[2] += bf2f_lo(v0.y) + bf2f_lo(v1.y) + bf2f_lo(v2.y) + bf2f_lo(v3.y);
        a[3] += bf2f_hi(v0.y) + bf2f_hi(v1.y) + bf2f_hi(v2.y) + bf2f_hi(v3.y);
        a[4] += bf2f_lo(v0.z) + bf2f_lo(v1.z) + bf2f_lo(v2.z) + bf2f_lo(v3.z);
        a[5] += bf2f_hi(v0.z) + bf2f_hi(v1.z) + bf2f_hi(v2.z) + bf2f_hi(v3.z);
        a[6] += bf2f_lo(v0.w) + bf2f_lo(v1.w) + bf2f_lo(v2.w) + bf2f_lo(v3.w);
        a[7] += bf2f_hi(v0.w) + bf2f_hi(v1.w) + bf2f_hi(v2.w) + bf2f_hi(v3.w);
    }
    for (; i < e1; ++i) {
        uint4 v = base[(size_t)ebuf[i] * 64 + lane];
        a[0] += bf2f_lo(v.x); a[1] += bf2f_hi(v.x);
        a[2] += bf2f_lo(v.y); a[3] += bf2f_hi(v.y);
        a[4] += bf2f_lo(v.z); a[5] += bf2f_hi(v.z);
        a[6] += bf2f_lo(v.w); a[7] += bf2f_hi(v.w);
    }
    float inv = 1.0f / fmaxf((float)(e1 - e0), 1.0f);
    uint4 o;
    o.x = f2bf(a[0] * inv) | (f2bf(a[1] * inv) << 16);
    o.y = f2bf(a[2] * inv) | (f2bf(a[3] * inv) << 16);
    o.z = f2bf(a[4] * inv) | (f2bf(a[5] * inv) << 16);
    o.w = f2bf(a[6] * inv) | (f2bf(a[7] * inv) << 16);
    ((uint4*)outb)[(size_t)w * 64 + lane] = o;
}

// ---------------- bf16 MFMA GEMM (XCD-swizzled, coalesced dbuf DMA) --------
// C = relu([A0b | A1b] @ Wb^T + b)
// mode 0: store C as bf16 to outb [N, C]
// mode 1: logit[row] += sum_col C[row,col] * Wo[col]
// 1D grid, id -> xcd=id&7, col=(id>>3)&3, row=(id>>5)*8+xcd: the 4 column
// siblings of each A row-tile run on ONE XCD -> A L2-resident, fetched once.
// Block 256 thr = 4 waves (2x2); tile 128x128; wave tile 64x64 (4x4 mfma);
// BK=32, double-buffered LDS, one barrier per iter.
// Staging: lane = 4r+j loads row (wave*32 [+16] + r)'s j-th 16B of its 64B
// K-slice -> 16 contiguous 64B segments per wave-instruction.
// LDS per buffer: row-major [128][32] bf16 tile (8 KB).
// REQUIRES K0 == K1 (multiples of 32), C == 512.
__global__ __launch_bounds__(256) void gemm_mfma(
    const unsigned short* __restrict__ A0,   // [N, K0] bf16
    const unsigned short* __restrict__ A1,   // [N, K1] bf16, K1 == K0
    const unsigned short* __restrict__ W,    // [C, K0+K1] bf16 row-major
    const float* __restrict__ b,             // [C] fp32
    unsigned short* __restrict__ outb,       // [N, C] bf16 (mode 0)
    const float* __restrict__ Wo,            // [C] fp32    (mode 1)
    float* __restrict__ logit,               // [N] fp32    (mode 1)
    int N, int K0, int K1, int C, int mode)
{
    // --- XCD-aware decode ---
    const int nrow = (N + 127) >> 7;
    const int id   = blockIdx.x;
    const int rowb = ((id >> 5) << 3) + (id & 7);   // rslot*8 + xcd
    const int colb = (id >> 3) & 3;
    if (rowb >= nrow) return;

    const int K = K0 + K1;
    const int S = K0;               // row stride of both A0 and A1
    __shared__ short As[2][4096];   // [128][32] per buffer, 8 KB
    __shared__ short Bs[2][4096];

    const int tid  = threadIdx.x;
    const int lane = tid & 63;
    const int wave = tid >> 6;
    const int wm = wave & 1, wn = wave >> 1;
    const int cl = lane & 15, quad = lane >> 4;
    const int row0 = rowb * 128;
    const int col0 = colb * 128;

    // staging: lane = 4r+j; wave w, load i covers tile rows w*32+i*16 .. +16
    const int r = lane >> 2;        // 0..15
    const int j = lane & 3;         // 16B chunk within the row's 64B K-slice
    const int trow0 = wave * 32 + r;
    const int trow1 = trow0 + 16;
    // clamp OOB tile rows to N-1 (loaded garbage discarded by epilogue guard)
    const int ar0 = (row0 + trow0 < N) ? row0 + trow0 : N - 1;
    const int ar1 = (row0 + trow1 < N) ? row0 + trow1 : N - 1;
    const size_t aoff0 = (size_t)ar0 * S + j * 8;
    const size_t aoff1 = (size_t)ar1 * S + j * 8;
    const size_t boff0 = (size_t)(col0 + trow0) * K + j * 8;
    const size_t boff1 = (size_t)(col0 + trow1) * K + j * 8;
    const int lds0 = (wave * 32) * 32;        // shorts; wave-uniform
    const int lds1 = (wave * 32 + 16) * 32;

    f32x4 acc[4][4];
    #pragma unroll
    for (int mt = 0; mt < 4; ++mt)
        #pragma unroll
        for (int nt = 0; nt < 4; ++nt)
            acc[mt][nt] = (f32x4){0.f, 0.f, 0.f, 0.f};

    // prologue: DMA tile 0 into buffer 0
    GLOAD_LDS16(A0 + aoff0, &As[0][lds0]);
    GLOAD_LDS16(A0 + aoff1, &As[0][lds1]);
    GLOAD_LDS16(W  + boff0, &Bs[0][lds0]);
    GLOAD_LDS16(W  + boff1, &Bs[0][lds1]);

    const int iters = K >> 5;
    for (int i = 0; i < iters; ++i) {
        const int cur = i & 1;
        // barrier drains tile i's DMA (vmcnt0) and fences tile i-1 frag reads
        __syncthreads();
        if (i + 1 < iters) {
            const int kn = (i + 1) << 5;
            const unsigned short* Ab = (kn < K0) ? (A0 + kn) : (A1 + (kn - K0));
            const unsigned short* Wb = W + kn;
            const int nb = cur ^ 1;
            GLOAD_LDS16(Ab + aoff0, &As[nb][lds0]);
            GLOAD_LDS16(Ab + aoff1, &As[nb][lds1]);
            GLOAD_LDS16(Wb + boff0, &Bs[nb][lds0]);
            GLOAD_LDS16(Wb + boff1, &Bs[nb][lds1]);
        }

        bf16x8 af[4], bfr[4];
        #pragma unroll
        for (int mt = 0; mt < 4; ++mt)
            af[mt] = *(const bf16x8*)&As[cur][(wm * 64 + mt * 16 + cl) * 32 + quad * 8];
        #pragma unroll
        for (int nt = 0; nt < 4; ++nt)
            bfr[nt] = *(const bf16x8*)&Bs[cur][(wn * 64 + nt * 16 + cl) * 32 + quad * 8];

        #pragma unroll
        for (int mt = 0; mt < 4; ++mt)
            #pragma unroll
            for (int nt = 0; nt < 4; ++nt)
                acc[mt][nt] = __builtin_amdgcn_mfma_f32_16x16x32_bf16(
                    af[mt], bfr[nt], acc[mt][nt], 0, 0, 0);
    }

    if (mode == 0) {
        #pragma unroll
        for (int nt = 0; nt < 4; ++nt) {
            const int colx = col0 + wn * 64 + nt * 16 + cl;
            const float bb = b[colx];
            #pragma unroll
            for (int mt = 0; mt < 4; ++mt) {
                #pragma unroll
                for (int rr = 0; rr < 4; ++rr) {
                    int row = row0 + wm * 64 + mt * 16 + quad * 4 + rr;
                    if (row < N)
                        outb[(size_t)row * C + colx] =
                            (unsigned short)f2bf(fmaxf(acc[mt][nt][rr] + bb, 0.0f));
                }
            }
        }
    } else {
        float bv[4], wv2[4];
        #pragma unroll
        for (int nt = 0; nt < 4; ++nt) {
            const int colx = col0 + wn * 64 + nt * 16 + cl;
            bv[nt] = b[colx];
            wv2[nt] = Wo[colx];
        }
        #pragma unroll
        for (int mt = 0; mt < 4; ++mt) {
            #pragma unroll
            for (int rr = 0; rr < 4; ++rr) {
                float s = 0.0f;
                #pragma unroll
                for (int nt = 0; nt < 4; ++nt)
                    s += fmaxf(acc[mt][nt][rr] + bv[nt], 0.0f) * wv2[nt];
                s += __shfl_xor(s, 1);
                s += __shfl_xor(s, 2);
                s += __shfl_xor(s, 4);
                s += __shfl_xor(s, 8);
                int row = row0 + wm * 64 + mt * 16 + quad * 4 + rr;
                if (cl == 0 && row < N) atomicAdd(&logit[row], s);
            }
        }
    }
}

__global__ void head_kernel(const float* __restrict__ logit, const float* __restrict__ bo,
                            float* __restrict__ out, int N) {
    int i = blockIdx.x * 256 + threadIdx.x;
    if (i < N) out[i] = 1.0f / (1.0f + expf(-(logit[i] + bo[0])));
}

extern "C" void kernel_launch(void* const* d_in, const int* in_sizes, int n_in,
                              void* d_out, int out_size, void* d_ws, size_t ws_size,
                              hipStream_t stream) {
    const float* x  = (const float*)d_in[0];
    const int*   ei = (const int*)d_in[1];
    const float* W1 = (const float*)d_in[2];
    const float* b1 = (const float*)d_in[3];
    const float* W2 = (const float*)d_in[4];
    const float* b2 = (const float*)d_in[5];
    const float* Wo = (const float*)d_in[6];
    const float* bo = (const float*)d_in[7];
    float* out = (float*)d_out;

    const int N = in_sizes[0] / 128;   // 50000
    const int E = in_sizes[1] / 2;     // 400000
    const int* src = ei;
    const int* dst = ei + E;

    char* ws = (char*)d_ws;
    size_t off = 0;
    auto alloc = [&](size_t bytes) {
        void* p = ws + off;
        off += (bytes + 255) & ~(size_t)255;
        return p;
    };
    int* deg      = (int*)alloc((size_t)N * 4);
    int* rowstart = (int*)alloc((size_t)(N + 1) * 4);
    int* cursor   = (int*)alloc((size_t)N * 4);
    int* partial  = (int*)alloc((size_t)64 * 4);
    int* ebuf     = (int*)alloc((size_t)E * 4);
    float* logit  = (float*)alloc((size_t)N * 4);
    unsigned short* xb  = (unsigned short*)alloc((size_t)N * 128 * 2);
    unsigned short* W1b = (unsigned short*)alloc((size_t)512 * 256 * 2);
    unsigned short* W2b = (unsigned short*)alloc((size_t)512 * 1024 * 2);
    unsigned short* n1b = (unsigned short*)alloc((size_t)N * 128 * 2);
    unsigned short* h1b = (unsigned short*)alloc((size_t)N * 512 * 2);
    unsigned short* n2b = (unsigned short*)alloc((size_t)N * 512 * 2);
    (void)ws_size; (void)n_in; (void)out_size;

    hipMemsetAsync(deg,   0, (size_t)N * 4, stream);
    hipMemsetAsync(logit, 0, (size_t)N * 4, stream);

    // conversions
    cvt_bf16_kernel<<<ceil_div(N * 128 / 4, 256), 256, 0, stream>>>(x, xb, N * 128 / 4);
    cvt_bf16_kernel<<<ceil_div(512 * 256 / 4, 256), 256, 0, stream>>>(W1, W1b, 512 * 256 / 4);
    cvt_bf16_kernel<<<ceil_div(512 * 1024 / 4, 256), 256, 0, stream>>>(W2, W2b, 512 * 1024 / 4);

    // CSR build (hierarchical scan)
    const int P = ceil_div(N, 1024);   // 49
    hist_kernel<<<ceil_div(E, 256), 256, 0, stream>>>(dst, deg, E);
    chunk_reduce<<<P, 256, 0, stream>>>(deg, partial, N);
    partial_scan<<<1, 64, 0, stream>>>(partial, rowstart + N, P);
    chunk_scan<<<P, 256, 0, stream>>>(deg, partial, rowstart, cursor, N);
    bucket_kernel<<<ceil_div(E, 256), 256, 0, stream>>>(src, dst, cursor, ebuf, E);

    // XCD-swizzled 1D grid: rows padded to x8, 4 col tiles, 8 xcd slots
    const int nrow = ceil_div(N, 128);              // 391
    const int gblocks = ceil_div(nrow, 8) * 8 * 4;  // 1568

    // layer 1
    gather_mean_128<<<ceil_div(N * 64, 256), 256, 0, stream>>>(rowstart, ebuf,
                                                               (const unsigned*)xb, (unsigned*)n1b, N);
    gemm_mfma<<<gblocks, 256, 0, stream>>>(xb, n1b, W1b, b1, h1b, nullptr, nullptr,
                                           N, 128, 128, 512, 0);

    // layer 2 + fused head
    gather_mean_512<<<ceil_div(N * 64, 256), 256, 0, stream>>>(rowstart, ebuf, h1b, n2b, N);
    gemm_mfma<<<gblocks, 256, 0, stream>>>(h1b, n2b, W2b, b2, nullptr, Wo, logit,
                                           N, 512, 512, 512, 1);

    head_kernel<<<ceil_div(N, 256), 256, 0, stream>>>(logit, bo, out, N);
}